// Round 1
// baseline (636.138 us; speedup 1.0000x reference)
//
#include <hip/hip_runtime.h>
#include <hip/hip_bf16.h>
#include <cstdint>
#include <cstddef>

// Problem constants (fixed by the reference):
#define HD   1024            // hidden H
#define NK   4               // heads K
#define DD   512             // H/2
#define LSEQ 2048            // L
#define NB   16              // B
#define MTOT (NB*LSEQ)       // 32768 tokens
#define N1   (HD*NK)         // 4096 projection width

typedef __attribute__((ext_vector_type(4))) float f32x4;
typedef __attribute__((ext_vector_type(8))) short bf16x8;

// async global->LDS, 16B per lane; LDS dest must be wave-uniform base (lane*16 auto)
#define GLOAD16(gp, lp) __builtin_amdgcn_global_load_lds( \
    (const __attribute__((address_space(1))) void*)(gp),  \
    (__attribute__((address_space(3))) void*)(lp), 16, 0, 0)

static __device__ __forceinline__ ushort f2bf(float f) {
  union { float f; unsigned u; } x; x.f = f;
  unsigned r = x.u + 0x7FFFu + ((x.u >> 16) & 1u);   // RNE
  return (ushort)(r >> 16);
}

// ---------------------------------------------------------------------------
// Mask dtype detector: bool-bytes vs int32. If int32, bytes at i%4!=0 are all 0.
// If bool bytes (~50% ones), many nonzero bytes at i%4!=0. Writes flag=1 for bytes.
__global__ void detect_mask_kernel(const unsigned char* __restrict__ m, int nbytes,
                                   int* __restrict__ flag) {
  int found = 0;
  for (int i = blockIdx.x * blockDim.x + threadIdx.x; i < nbytes;
       i += gridDim.x * blockDim.x)
    if ((i & 3) && m[i]) found = 1;
  if (__any(found) && (threadIdx.x & 63) == 0) atomicOr(flag, 1);
}

// ---------------------------------------------------------------------------
__global__ void cvt_f32_bf16_kernel(const float* __restrict__ src,
                                    ushort* __restrict__ dst, long n) {
  long stride = (long)gridDim.x * blockDim.x * 4;
  for (long i = ((long)blockIdx.x * blockDim.x + threadIdx.x) * 4; i < n; i += stride) {
    f32x4 v = *(const f32x4*)(src + i);
    ushort4 o; o.x = f2bf(v.x); o.y = f2bf(v.y); o.z = f2bf(v.z); o.w = f2bf(v.w);
    *(ushort4*)(dst + i) = o;
  }
}

// dst[c][r] = bf16(src[r][c]); grid.z = batch
__global__ void transpose_cvt_kernel(const float* __restrict__ src,
                                     ushort* __restrict__ dst,
                                     int R, int C, long sBatch, long dBatch) {
  __shared__ float tile[32][33];
  const float* s = src + blockIdx.z * sBatch;
  ushort* d = dst + blockIdx.z * dBatch;
  int c0 = blockIdx.x * 32, r0 = blockIdx.y * 32;
  int tx = threadIdx.x, ty = threadIdx.y;  // (32, 8)
  #pragma unroll
  for (int i = 0; i < 32; i += 8)
    tile[ty + i][tx] = s[(long)(r0 + ty + i) * C + (c0 + tx)];
  __syncthreads();
  #pragma unroll
  for (int i = 0; i < 32; i += 8)
    d[(long)(c0 + ty + i) * R + (r0 + tx)] = f2bf(tile[tx][ty + i]);
}

// ---------------------------------------------------------------------------
// 128x128 tile bf16 MFMA GEMM, BK=32, 4 waves (2x2 of 64x64), global_load_lds staging.
// A: [M,lda] bf16 row-major. Bt: [N,ldb] bf16 row-major (pre-transposed weights).
// MODE 0: Cout[row*ldc+col] = bf16(acc)   (proj)
// MODE 1: logits[head*MTOT + m0glob+row] += sum_col tanh(acc+b1)*W2 (per-head)
template<int MODE>
__global__ __launch_bounds__(256, 2)
void mfma_gemm_kernel(const ushort* __restrict__ A, int lda,
                      const ushort* __restrict__ Bt, int ldb, int Kdim,
                      ushort* __restrict__ Cout, int ldc,
                      const float* __restrict__ b1, const float* __restrict__ W2,
                      float* __restrict__ logitsOut, int m0glob) {
  __shared__ ushort As[128 * 32];
  __shared__ ushort Bs[128 * 32];
  const int tid = threadIdx.x;
  const int wave = tid >> 6, lane = tid & 63;
  const int head = blockIdx.z;
  const int m0 = blockIdx.x * 128, n0 = blockIdx.y * 128;
  const int wr = wave >> 1, wc = wave & 1;

  const ushort* Ap = (MODE == 1) ? (A + head * HD) : A;
  const ushort* Bp = (MODE == 1) ? (Bt + (long)head * DD * HD) : Bt;

  f32x4 acc[4][4] = {};

  // staging map: per issue i in {0,1}: row = i*64 + wave*16 + lane/4, col8 = lane%4
  const int stRow = wave * 16 + (lane >> 2);
  const int stCol = (lane & 3) * 8;
  const int ldsOff = wave * 1024;  // bytes; + i*4096

  const int ksteps = Kdim >> 5;
  for (int kt = 0; kt < ksteps; ++kt) {
    const int kk = (kt << 5) + stCol;
    GLOAD16(Ap + (long)(m0 + stRow) * lda + kk,      (char*)As + ldsOff);
    GLOAD16(Ap + (long)(m0 + 64 + stRow) * lda + kk, (char*)As + 4096 + ldsOff);
    GLOAD16(Bp + (long)(n0 + stRow) * ldb + kk,      (char*)Bs + ldsOff);
    GLOAD16(Bp + (long)(n0 + 64 + stRow) * ldb + kk, (char*)Bs + 4096 + ldsOff);
    __syncthreads();  // drains vmcnt -> staged data visible

    bf16x8 aF[4], bF[4];
    const int rsel = lane & 15, kByte = (lane >> 4) << 4;
    #pragma unroll
    for (int m = 0; m < 4; ++m)
      aF[m] = *(const bf16x8*)((const char*)As + ((wr * 64 + m * 16 + rsel) * 64 + kByte));
    #pragma unroll
    for (int n = 0; n < 4; ++n)
      bF[n] = *(const bf16x8*)((const char*)Bs + ((wc * 64 + n * 16 + rsel) * 64 + kByte));
    #pragma unroll
    for (int m = 0; m < 4; ++m)
      #pragma unroll
      for (int n = 0; n < 4; ++n)
        acc[m][n] = __builtin_amdgcn_mfma_f32_16x16x32_bf16(aF[m], bF[n], acc[m][n], 0, 0, 0);
    __syncthreads();  // all reads done before next stage overwrites
  }

  if constexpr (MODE == 0) {
    #pragma unroll
    for (int m = 0; m < 4; ++m)
      #pragma unroll
      for (int n = 0; n < 4; ++n) {
        int col = n0 + wc * 64 + n * 16 + (lane & 15);
        #pragma unroll
        for (int r = 0; r < 4; ++r) {
          int row = m0 + wr * 64 + m * 16 + ((lane >> 4) << 2) + r;
          Cout[(long)row * ldc + col] = f2bf(acc[m][n][r]);
        }
      }
  } else {
    float b1v[4], w2v[4];
    #pragma unroll
    for (int n = 0; n < 4; ++n) {
      int col = n0 + wc * 64 + n * 16 + (lane & 15);
      b1v[n] = b1[head * DD + col];
      w2v[n] = W2[head * DD + col];
    }
    #pragma unroll
    for (int m = 0; m < 4; ++m)
      #pragma unroll
      for (int r = 0; r < 4; ++r) {
        float s = 0.f;
        #pragma unroll
        for (int n = 0; n < 4; ++n)
          s += tanhf(acc[m][n][r] + b1v[n]) * w2v[n];
        s += __shfl_xor(s, 1, 64);
        s += __shfl_xor(s, 2, 64);
        s += __shfl_xor(s, 4, 64);
        s += __shfl_xor(s, 8, 64);
        if ((lane & 15) == 0) {
          int row = m0glob + m0 + wr * 64 + m * 16 + ((lane >> 4) << 2) + r;
          atomicAdd(&logitsOut[(long)head * MTOT + row], s);
        }
      }
  }
}

// ---------------------------------------------------------------------------
// masked softmax over L per (k,b) row; out flat [K][B][L] == logits flat layout
__global__ __launch_bounds__(256)
void masked_softmax_kernel(const float* __restrict__ logits,
                           const unsigned char* __restrict__ maskB,
                           const int* __restrict__ maskI,
                           const int* __restrict__ flag,
                           float* __restrict__ out) {
  const int kb = blockIdx.x;          // k*NB + b
  const int b = kb & (NB - 1);
  const long base = (long)kb * LSEQ;
  const bool isByte = (*flag != 0);
  const int tid = threadIdx.x;

  float x[8];
  float mx = -3.0e38f;
  #pragma unroll
  for (int j = 0; j < 8; ++j) {
    int l = tid + j * 256;
    bool msk = isByte ? (maskB[b * LSEQ + l] != 0) : (maskI[b * LSEQ + l] != 0);
    float v = msk ? -1e9f : logits[base + l];
    x[j] = v; mx = fmaxf(mx, v);
  }
  __shared__ float redm[4], reds[4];
  #pragma unroll
  for (int off = 32; off >= 1; off >>= 1) mx = fmaxf(mx, __shfl_xor(mx, off, 64));
  if ((tid & 63) == 0) redm[tid >> 6] = mx;
  __syncthreads();
  mx = fmaxf(fmaxf(redm[0], redm[1]), fmaxf(redm[2], redm[3]));

  float sum = 0.f;
  #pragma unroll
  for (int j = 0; j < 8; ++j) { x[j] = __expf(x[j] - mx); sum += x[j]; }
  #pragma unroll
  for (int off = 32; off >= 1; off >>= 1) sum += __shfl_xor(sum, off, 64);
  if ((tid & 63) == 0) reds[tid >> 6] = sum;
  __syncthreads();
  sum = reds[0] + reds[1] + reds[2] + reds[3];

  float inv = 1.0f / sum;
  #pragma unroll
  for (int j = 0; j < 8; ++j) out[base + tid + j * 256] = x[j] * inv;
}

// ---------------------------------------------------------------------------
extern "C" void kernel_launch(void* const* d_in, const int* in_sizes, int n_in,
                              void* d_out, int out_size, void* d_ws, size_t ws_size,
                              hipStream_t stream) {
  const float* hidden = (const float*)d_in[0];
  const void*  masks  = d_in[1];
  const float* Wp     = (const float*)d_in[2];
  const float* W1     = (const float*)d_in[3];
  const float* b1     = (const float*)d_in[4];
  const float* W2     = (const float*)d_in[5];
  float* out = (float*)d_out;

  // workspace layout (bytes)
  char* ws = (char*)d_ws;
  ushort* WpT      = (ushort*)(ws + 0);                 //  8,388,608  [4096][1024] bf16
  ushort* W1T      = (ushort*)(ws + 8388608);           //  4,194,304  [4][512][1024] bf16
  float*  logits   = (float*) (ws + 12582912);          //    524,288  [4][32768] f32
  int*    flag     = (int*)   (ws + 13107200);          //        256
  ushort* hiddenBf = (ushort*)(ws + 13107456);          // 67,108,864  [32768][1024] bf16
  char*   projBase = ws + 80216320;                     // chunkM*4096 bf16

  size_t fixedBytes = 80216320;
  size_t avail = (ws_size > fixedBytes) ? (ws_size - fixedBytes) : 0;
  long chunkM = (long)(avail / ((long)N1 * 2)) & ~127L;
  if (chunkM > MTOT) chunkM = MTOT;
  if (chunkM < 128) chunkM = 128;  // requires ws_size >= ~81 MB
  ushort* proj = (ushort*)projBase;

  // zero logits + flag (single contiguous region)
  hipMemsetAsync(ws + 12582912, 0, 524288 + 256, stream);

  detect_mask_kernel<<<8, 256, 0, stream>>>((const unsigned char*)masks, NB * LSEQ, flag);
  cvt_f32_bf16_kernel<<<2048, 256, 0, stream>>>(hidden, hiddenBf, (long)MTOT * HD);
  dim3 tb(32, 8);
  transpose_cvt_kernel<<<dim3(N1 / 32, HD / 32, 1), tb, 0, stream>>>(
      Wp, WpT, HD, N1, 0, 0);
  transpose_cvt_kernel<<<dim3(DD / 32, HD / 32, NK), tb, 0, stream>>>(
      W1, W1T, HD, DD, (long)HD * DD, (long)DD * HD);

  for (long m0 = 0; m0 < MTOT; m0 += chunkM) {
    long cm = chunkM; if (m0 + cm > MTOT) cm = MTOT - m0;
    // GEMM1: proj[cm,4096] = hidden[m0:m0+cm] @ Wp   (bf16 out)
    mfma_gemm_kernel<0><<<dim3(cm / 128, N1 / 128, 1), 256, 0, stream>>>(
        hiddenBf + m0 * HD, HD, WpT, HD, HD, proj, N1,
        nullptr, nullptr, nullptr, 0);
    // GEMM2 (+tanh+W2 dot): logits[k, m0:m0+cm] += ...
    mfma_gemm_kernel<1><<<dim3(cm / 128, DD / 128, NK), 256, 0, stream>>>(
        proj, N1, W1T, HD, HD, nullptr, 0,
        b1, W2, logits, (int)m0);
  }

  masked_softmax_kernel<<<NK * NB, 256, 0, stream>>>(
      logits, (const unsigned char*)masks, (const int*)masks, flag, out);
}

// Round 2
// 565.104 us; speedup vs baseline: 1.1257x; 1.1257x over previous
//
#include <hip/hip_runtime.h>
#include <hip/hip_bf16.h>
#include <cstdint>
#include <cstddef>

// Problem constants (fixed by the reference):
#define HD   1024            // hidden H
#define NK   4               // heads K
#define DD   512             // H/2
#define LSEQ 2048            // L
#define NB   16              // B
#define MTOT (NB*LSEQ)       // 32768 tokens
#define N1   (HD*NK)         // 4096 projection width

typedef __attribute__((ext_vector_type(4))) float f32x4;
typedef __attribute__((ext_vector_type(8))) short bf16x8;

// async global->LDS, 16B per lane; LDS dest is wave-uniform base + lane*16
#define GLOAD16(gp, lp) __builtin_amdgcn_global_load_lds( \
    (const __attribute__((address_space(1))) void*)(gp),  \
    (__attribute__((address_space(3))) void*)(lp), 16, 0, 0)

static __device__ __forceinline__ ushort f2bf(float f) {
  union { float f; unsigned u; } x; x.f = f;
  unsigned r = x.u + 0x7FFFu + ((x.u >> 16) & 1u);   // RNE
  return (ushort)(r >> 16);
}

// ---------------------------------------------------------------------------
__global__ void detect_mask_kernel(const unsigned char* __restrict__ m, int nbytes,
                                   int* __restrict__ flag) {
  int found = 0;
  for (int i = blockIdx.x * blockDim.x + threadIdx.x; i < nbytes;
       i += gridDim.x * blockDim.x)
    if ((i & 3) && m[i]) found = 1;
  if (__any(found) && (threadIdx.x & 63) == 0) atomicOr(flag, 1);
}

// ---------------------------------------------------------------------------
__global__ void cvt_f32_bf16_kernel(const float* __restrict__ src,
                                    ushort* __restrict__ dst, long n) {
  long stride = (long)gridDim.x * blockDim.x * 4;
  for (long i = ((long)blockIdx.x * blockDim.x + threadIdx.x) * 4; i < n; i += stride) {
    f32x4 v = *(const f32x4*)(src + i);
    ushort4 o; o.x = f2bf(v.x); o.y = f2bf(v.y); o.z = f2bf(v.z); o.w = f2bf(v.w);
    *(ushort4*)(dst + i) = o;
  }
}

// dst[c][r] = bf16(src[r][c]); grid.z = batch
__global__ void transpose_cvt_kernel(const float* __restrict__ src,
                                     ushort* __restrict__ dst,
                                     int R, int C, long sBatch, long dBatch) {
  __shared__ float tile[32][33];
  const float* s = src + blockIdx.z * sBatch;
  ushort* d = dst + blockIdx.z * dBatch;
  int c0 = blockIdx.x * 32, r0 = blockIdx.y * 32;
  int tx = threadIdx.x, ty = threadIdx.y;  // (32, 8)
  #pragma unroll
  for (int i = 0; i < 32; i += 8)
    tile[ty + i][tx] = s[(long)(r0 + ty + i) * C + (c0 + tx)];
  __syncthreads();
  #pragma unroll
  for (int i = 0; i < 32; i += 8)
    d[(long)(c0 + ty + i) * R + (r0 + tx)] = f2bf(tile[tx][ty + i]);
}

// ---------------------------------------------------------------------------
// 256x256 tile, BK=64, 8-phase-style schedule (4 phases/K-tile, counted vmcnt),
// 8 waves (2Mx4N), per-wave 128x64 output, LDS 128KB as 4 K-half slots/operand.
// A: [M,lda] bf16 row-major. Bt: [N,ldb] bf16 row-major (pre-transposed).
// MODE 0: Cout[row*ldc+col] = bf16(acc)
// MODE 1: logits[head*MTOT + m0glob+row] += sum_col tanh(acc+b1)*W2
template<int MODE>
__global__ __launch_bounds__(512, 2)
void gemm256_kernel(const ushort* __restrict__ A, int lda,
                    const ushort* __restrict__ Bt, int ldb, int Kdim,
                    ushort* __restrict__ Cout, int ldc,
                    const float* __restrict__ b1, const float* __restrict__ W2,
                    float* __restrict__ logitsOut, int m0glob) {
  // A slots: 4 x 16KB at [0..65536); B slots: 4 x 16KB at [65536..131072)
  __shared__ __align__(16) char lds[131072];

  const int tid = threadIdx.x;
  const int w = tid >> 6, lane = tid & 63;
  const int head = blockIdx.z;

  // XCD-aware swizzle of linear block id (bijective only when nwg%8==0)
  int bid = blockIdx.x + gridDim.x * blockIdx.y;
  const int nwg = gridDim.x * gridDim.y;
  if ((nwg & 7) == 0) {
    const int q = nwg >> 3;
    bid = (bid & 7) * q + (bid >> 3);
  }
  const int nMB = gridDim.x;
  const int m0 = (bid % nMB) * 256;
  const int n0 = (bid / nMB) * 256;

  const ushort* Ap = (MODE == 1) ? (A + head * HD) : A;
  const ushort* Bp = (MODE == 1) ? (Bt + (long)head * DD * HD) : Bt;
  const ushort* Ag = Ap + (long)m0 * lda;
  const ushort* Bg = Bp + (long)n0 * ldb;

  // wave tile: wm in {0,1} -> 128 M-rows; wn in {0..3} -> 64 N-cols
  const int wm = w >> 2, wn = w & 3;
  const int rsel = lane & 15;
  // read-side swizzle: chunk ^= (row>>1)&3 ; lane-constant since frag bases %16==0
  const int chunkC = ((lane >> 4) ^ ((rsel >> 1) & 3)) << 4;
  const int laneA = wm * 8192 + rsel * 64 + chunkC;           // within A slot
  const int laneB = 65536 + wn * 4096 + rsel * 64 + chunkC;   // B region + within slot

  // staging: thread issues 2 x 16B; linear LDS dest, inverse-swizzled global src
  const int stCg = ((lane & 3) ^ ((lane >> 3) & 3)) * 8;      // global col chunk (elems)
  const int stR0 = (w * 2) * 16 + (lane >> 2);                // rows for j=0,1: stR0, stR0+16
  const int stDst0 = (w * 2) * 1024;                          // + j*1024

  #define STAGE(gbase, ld, slotByte, ktile, kh)                                   \
    {                                                                             \
      _Pragma("unroll")                                                           \
      for (int j = 0; j < 2; ++j) {                                               \
        const ushort* gp = (gbase) + (long)(stR0 + j * 16) * (ld) +               \
                           ((ktile) << 6) + ((kh) << 5) + stCg;                   \
        GLOAD16(gp, lds + (slotByte) + stDst0 + j * 1024);                        \
      }                                                                           \
    }

  f32x4 acc[8][4] = {};

  // prologue: stage tile 0, both K-halves
  STAGE(Ag, lda, 0,             0, 0);
  STAGE(Bg, ldb, 65536,         0, 0);
  STAGE(Ag, lda, 16384,         0, 1);
  STAGE(Bg, ldb, 65536 + 16384, 0, 1);
  asm volatile("s_waitcnt vmcnt(4)" ::: "memory");
  __builtin_amdgcn_sched_barrier(0);
  __builtin_amdgcn_s_barrier();

  const int nt = Kdim >> 6;   // K-tiles of 64
  for (int t = 0; t < nt; ++t) {
    const int ts = (t + 1 < nt) ? t + 1 : t;          // clamped prefetch tile
    const int s0 = (2 * t) & 3, s1 = (2 * t + 1) & 3; // compute slots (kh0, kh1)
    const int p0 = (2 * t + 2) & 3, p1 = (2 * t + 3) & 3; // prefetch dest slots
    bf16x8 aF[4], bB[4];
    #pragma unroll
    for (int q = 0; q < 4; ++q) {
      const int kk = q >> 1, mh = q & 1;
      const int slot = (kk ? s1 : s0) * 16384;
      if (mh == 0) {
        #pragma unroll
        for (int nf = 0; nf < 4; ++nf)
          bB[nf] = *(const bf16x8*)(lds + slot + laneB + nf * 1024);
      }
      #pragma unroll
      for (int mf = 0; mf < 4; ++mf)
        aF[mf] = *(const bf16x8*)(lds + slot + laneA + mh * 4096 + mf * 1024);
      if (q == 0)      STAGE(Ag, lda, p0 * 16384,         ts, 0)
      else if (q == 1) STAGE(Bg, ldb, 65536 + p0 * 16384, ts, 0)
      else if (q == 2) STAGE(Ag, lda, p1 * 16384,         ts, 1)
      else             STAGE(Bg, ldb, 65536 + p1 * 16384, ts, 1)
      __builtin_amdgcn_s_barrier();
      __builtin_amdgcn_s_setprio(1);
      #pragma unroll
      for (int mf = 0; mf < 4; ++mf)
        #pragma unroll
        for (int nf = 0; nf < 4; ++nf)
          acc[mh * 4 + mf][nf] = __builtin_amdgcn_mfma_f32_16x16x32_bf16(
              aF[mf], bB[nf], acc[mh * 4 + mf][nf], 0, 0, 0);
      __builtin_amdgcn_s_setprio(0);
      if (q & 1) {
        asm volatile("s_waitcnt vmcnt(4)" ::: "memory");
        __builtin_amdgcn_sched_barrier(0);
      }
      __builtin_amdgcn_s_barrier();
    }
  }

  if constexpr (MODE == 0) {
    #pragma unroll
    for (int mf = 0; mf < 8; ++mf)
      #pragma unroll
      for (int nf = 0; nf < 4; ++nf) {
        const int col = n0 + wn * 64 + nf * 16 + (lane & 15);
        #pragma unroll
        for (int r = 0; r < 4; ++r) {
          const int row = m0 + wm * 128 + mf * 16 + ((lane >> 4) << 2) + r;
          Cout[(long)row * ldc + col] = f2bf(acc[mf][nf][r]);
        }
      }
  } else {
    float b1v[4], w2v[4];
    #pragma unroll
    for (int nf = 0; nf < 4; ++nf) {
      const int col = n0 + wn * 64 + nf * 16 + (lane & 15);
      b1v[nf] = b1[head * DD + col];
      w2v[nf] = W2[head * DD + col];
    }
    #pragma unroll
    for (int mf = 0; mf < 8; ++mf)
      #pragma unroll
      for (int r = 0; r < 4; ++r) {
        float s = 0.f;
        #pragma unroll
        for (int nf = 0; nf < 4; ++nf)
          s += tanhf(acc[mf][nf][r] + b1v[nf]) * w2v[nf];
        s += __shfl_xor(s, 1, 64);
        s += __shfl_xor(s, 2, 64);
        s += __shfl_xor(s, 4, 64);
        s += __shfl_xor(s, 8, 64);
        if ((lane & 15) == 0) {
          const int row = m0glob + m0 + wm * 128 + mf * 16 + ((lane >> 4) << 2) + r;
          atomicAdd(&logitsOut[(long)head * MTOT + row], s);
        }
      }
  }
  #undef STAGE
}

// ---------------------------------------------------------------------------
// masked softmax over L per (k,b) row; out flat [K][B][L] == logits flat layout
__global__ __launch_bounds__(256)
void masked_softmax_kernel(const float* __restrict__ logits,
                           const unsigned char* __restrict__ maskB,
                           const int* __restrict__ maskI,
                           const int* __restrict__ flag,
                           float* __restrict__ out) {
  const int kb = blockIdx.x;          // k*NB + b
  const int b = kb & (NB - 1);
  const long base = (long)kb * LSEQ;
  const bool isByte = (*flag != 0);
  const int tid = threadIdx.x;

  float x[8];
  float mx = -3.0e38f;
  #pragma unroll
  for (int j = 0; j < 8; ++j) {
    int l = tid + j * 256;
    bool msk = isByte ? (maskB[b * LSEQ + l] != 0) : (maskI[b * LSEQ + l] != 0);
    float v = msk ? -1e9f : logits[base + l];
    x[j] = v; mx = fmaxf(mx, v);
  }
  __shared__ float redm[4], reds[4];
  #pragma unroll
  for (int off = 32; off >= 1; off >>= 1) mx = fmaxf(mx, __shfl_xor(mx, off, 64));
  if ((tid & 63) == 0) redm[tid >> 6] = mx;
  __syncthreads();
  mx = fmaxf(fmaxf(redm[0], redm[1]), fmaxf(redm[2], redm[3]));

  float sum = 0.f;
  #pragma unroll
  for (int j = 0; j < 8; ++j) { x[j] = __expf(x[j] - mx); sum += x[j]; }
  #pragma unroll
  for (int off = 32; off >= 1; off >>= 1) sum += __shfl_xor(sum, off, 64);
  if ((tid & 63) == 0) reds[tid >> 6] = sum;
  __syncthreads();
  sum = reds[0] + reds[1] + reds[2] + reds[3];

  float inv = 1.0f / sum;
  #pragma unroll
  for (int j = 0; j < 8; ++j) out[base + tid + j * 256] = x[j] * inv;
}

// ---------------------------------------------------------------------------
extern "C" void kernel_launch(void* const* d_in, const int* in_sizes, int n_in,
                              void* d_out, int out_size, void* d_ws, size_t ws_size,
                              hipStream_t stream) {
  const float* hidden = (const float*)d_in[0];
  const void*  masks  = d_in[1];
  const float* Wp     = (const float*)d_in[2];
  const float* W1     = (const float*)d_in[3];
  const float* b1     = (const float*)d_in[4];
  const float* W2     = (const float*)d_in[5];
  float* out = (float*)d_out;

  // workspace layout (bytes)
  char* ws = (char*)d_ws;
  ushort* WpT      = (ushort*)(ws + 0);                 //  8,388,608  [4096][1024] bf16
  ushort* W1T      = (ushort*)(ws + 8388608);           //  4,194,304  [4][512][1024] bf16
  float*  logits   = (float*) (ws + 12582912);          //    524,288  [4][32768] f32
  int*    flag     = (int*)   (ws + 13107200);          //        256
  ushort* hiddenBf = (ushort*)(ws + 13107456);          // 67,108,864  [32768][1024] bf16
  char*   projBase = ws + 80216320;                     // chunkM*4096 bf16

  size_t fixedBytes = 80216320;
  size_t avail = (ws_size > fixedBytes) ? (ws_size - fixedBytes) : 0;
  long chunkM = (long)(avail / ((long)N1 * 2)) & ~255L;
  if (chunkM > MTOT) chunkM = MTOT;
  if (chunkM < 256) chunkM = 256;  // requires ws_size >= ~82 MB
  ushort* proj = (ushort*)projBase;

  // zero logits + flag (single contiguous region)
  hipMemsetAsync(ws + 12582912, 0, 524288 + 256, stream);

  detect_mask_kernel<<<8, 256, 0, stream>>>((const unsigned char*)masks, NB * LSEQ, flag);
  cvt_f32_bf16_kernel<<<2048, 256, 0, stream>>>(hidden, hiddenBf, (long)MTOT * HD);
  dim3 tb(32, 8);
  transpose_cvt_kernel<<<dim3(N1 / 32, HD / 32, 1), tb, 0, stream>>>(
      Wp, WpT, HD, N1, 0, 0);
  transpose_cvt_kernel<<<dim3(DD / 32, HD / 32, NK), tb, 0, stream>>>(
      W1, W1T, HD, DD, (long)HD * DD, (long)DD * HD);

  for (long m0 = 0; m0 < MTOT; m0 += chunkM) {
    long cm = chunkM; if (m0 + cm > MTOT) cm = MTOT - m0;
    // GEMM1: proj[cm,4096] = hidden[m0:m0+cm] @ Wp   (bf16 out)
    gemm256_kernel<0><<<dim3(cm / 256, N1 / 256, 1), 512, 0, stream>>>(
        hiddenBf + m0 * HD, HD, WpT, HD, HD, proj, N1,
        nullptr, nullptr, nullptr, 0);
    // GEMM2 (+tanh+W2 dot): logits[k, m0:m0+cm] += ...
    gemm256_kernel<1><<<dim3(cm / 256, DD / 256, NK), 512, 0, stream>>>(
        proj, N1, W1T, HD, HD, nullptr, 0,
        b1, W2, logits, (int)m0);
  }

  masked_softmax_kernel<<<NK * NB, 256, 0, stream>>>(
      logits, (const unsigned char*)masks, (const int*)masks, flag, out);
}